// Round 3
// baseline (637.665 us; speedup 1.0000x reference)
//
#include <hip/hip_runtime.h>

#define BS  16
#define TT  50
#define NN  100
#define OBSF 40
#define ACTF 8
#define HIDF 64
#define LATF 16

__device__ __forceinline__ float sigmf(float x) { return 1.f / (1.f + __expf(-x)); }
__device__ __forceinline__ float tanh_fast(float x) { return 1.f - 2.f / (__expf(2.f * x) + 1.f); }

// ---------------------------------------------------------------- adj bitmask
__global__ void adjmask_kernel(const int* __restrict__ adj, unsigned long long* __restrict__ mask) {
    int n = threadIdx.x;
    if (n < NN) {
        unsigned long long w0 = 0ull, w1 = 0ull;
        for (int m = 0; m < 64; ++m)  if (adj[n * NN + m] > 0) w0 |= (1ull << m);
        for (int m = 64; m < NN; ++m) if (adj[n * NN + m] > 0) w1 |= (1ull << (m - 64));
        mask[2 * n] = w0; mask[2 * n + 1] = w1;
    }
}

// ---------------------------------------------------------------- embedding
__global__ void emb_kernel(const float* __restrict__ o, const float* __restrict__ ap,
                           const float* __restrict__ mk,
                           const float* __restrict__ Wobs, const float* __restrict__ bobs,
                           const float* __restrict__ Wpa, const float* __restrict__ bpa,
                           const float* __restrict__ Wmk, const float* __restrict__ bmk,
                           const float* __restrict__ idemb, float* __restrict__ emb) {
    int g = blockIdx.x;               // (b*T+t)*N + n
    int n = g % NN;
    int j = threadIdx.x;              // 0..63
    __shared__ float so[OBSF], sa[ACTF], sm[ACTF];
    if (j < OBSF) so[j] = o[(size_t)g * OBSF + j];
    if (j >= 40 && j < 48) sa[j - 40] = ap[(size_t)g * ACTF + (j - 40)];
    if (j >= 48 && j < 56) sm[j - 48] = mk[(size_t)g * ACTF + (j - 48)];
    __syncthreads();
    float acc = bobs[j] + bpa[j] + bmk[j] + idemb[n * HIDF + j];
    #pragma unroll
    for (int k = 0; k < OBSF; ++k) acc += so[k] * Wobs[k * HIDF + j];
    #pragma unroll
    for (int k = 0; k < ACTF; ++k) acc += sa[k] * Wpa[k * HIDF + j] + sm[k] * Wmk[k * HIDF + j];
    emb[(size_t)g * HIDF + j] = acc;
}

// ---------------------------------------------------------------- xW = x @ Wih + bih + bhh
__global__ void xw_kernel(const float* __restrict__ emb, const float* __restrict__ Wih,
                          const float* __restrict__ bih, const float* __restrict__ bhh,
                          float* __restrict__ xW) {
    int blk = blockIdx.x;
    int chunk = blk % 5;
    int s = blk / 5;
    int b = s / NN, n = s % NN;
    int t0 = chunk * 10;
    __shared__ float se[10][HIDF];
    int tid = threadIdx.x;
    for (int i = tid; i < 10 * HIDF; i += 256) {
        int r = i >> 6, k = i & 63;
        se[r][k] = emb[((size_t)(b * TT + t0 + r) * NN + n) * HIDF + k];
    }
    __syncthreads();
    int j = tid;
    float base = bih[j] + bhh[j];
    float acc[10];
    #pragma unroll
    for (int r = 0; r < 10; ++r) acc[r] = base;
    for (int k = 0; k < HIDF; ++k) {
        float w = Wih[k * 256 + j];
        #pragma unroll
        for (int r = 0; r < 10; ++r) acc[r] += se[r][k] * w;
    }
    #pragma unroll
    for (int r = 0; r < 10; ++r) xW[((size_t)s * TT + t0 + r) * 256 + j] = acc[r];
}

// ---------------------------------------------------------------- LSTM recurrence
// One barrier per timestep. Lane l of EVERY wave holds a redundant copy of
// h[l], c[l] in registers; the h-broadcast for the gemv is v_readlane (no LDS,
// no extra barrier). gs is double-buffered on timestep parity so the single
// barrier is race-free.
__launch_bounds__(256)
__global__ void lstm_kernel(const float* __restrict__ xW, const float* __restrict__ Whh,
                            float* __restrict__ xenc) {
    int s = blockIdx.x;
    int b = s / NN, n = s % NN;
    int tid = threadIdx.x;
    int lane = tid & 63;
    __shared__ float gs[2][256];
    float wcol[HIDF];
    #pragma unroll
    for (int k = 0; k < HIDF; ++k) wcol[k] = Whh[k * 256 + tid];
    float h = 0.f, c = 0.f;                 // lane l: h[l], c[l] (per-wave copy)
    const float* xp = xW + (size_t)s * TT * 256 + tid;
    float* xe = xenc + ((size_t)b * TT * NN + n) * HIDF + lane;   // wave 0 stores
    for (int t = 0; t < TT; ++t) {
        float acc = xp[(size_t)t * 256];
        #pragma unroll
        for (int k = 0; k < HIDF; ++k) {
            float hk = __int_as_float(__builtin_amdgcn_readlane(__float_as_int(h), k));
            acc += hk * wcol[k];
        }
        gs[t & 1][tid] = acc;
        __syncthreads();
        float gi = gs[t & 1][lane];
        float gf = gs[t & 1][64 + lane];
        float gg = gs[t & 1][128 + lane];
        float go = gs[t & 1][192 + lane];
        c = sigmf(gf) * c + sigmf(gi) * tanh_fast(gg);
        h = sigmf(go) * tanh_fast(c);
        if (tid < 64) xe[(size_t)t * NN * HIDF] = h;
    }
}

// ---------------------------------------------------------------- fused GAT layer
// sh aliases sx (phase-1 result staged in registers). Single-pass softmax (no max),
// branchless mask, float4 LDS/global. SPLIT divides FOUT across threads in phase 2.
// OUTMODE 0: concat heads + elu(+bias); 1: single head + bias; 2: +bias then * mgate
template <int FIN1, int FIN2, int H, int FOUT, int SPLIT, int OUTMODE>
__launch_bounds__(256)
__global__ void gat_kernel(const float* __restrict__ x1, const float* __restrict__ x2,
                           const float* __restrict__ w, const float* __restrict__ asrc,
                           const float* __restrict__ adst, const float* __restrict__ bias,
                           const unsigned long long* __restrict__ adjmask,
                           const float* __restrict__ mgate, float* __restrict__ out) {
    constexpr int FIN = FIN1 + FIN2;
    constexpr int HF = H * FOUT;
    constexpr int NPT = 256 / HF;                    // rows in flight (4 / 8 / 32)
    constexpr int ROWS = (NN + NPT - 1) / NPT;       // 25 / 13 / 4
    constexpr int SB = NN * (FIN > HF ? FIN : HF);
    __shared__ __align__(16) float sbuf[SB];         // sx, later aliased as sh
    __shared__ __align__(16) float ses[H * NN];
    __shared__ __align__(16) float sed[H * NN];
    __shared__ unsigned long long smask[2 * NN];
    int g = blockIdx.x;
    int tid = threadIdx.x;

    for (int i = tid; i < NN * FIN1; i += 256) {
        int n = i / FIN1, k = i % FIN1;
        sbuf[n * FIN + k] = x1[((size_t)g * NN + n) * FIN1 + k];
    }
    if constexpr (FIN2 > 0) {
        for (int i = tid; i < NN * FIN2; i += 256) {
            int n = i / FIN2, k = i % FIN2;
            sbuf[n * FIN + FIN1 + k] = x2[(size_t)g * FIN2 + k];
        }
    }
    if (tid < 2 * NN) smask[tid] = adjmask[tid];
    __syncthreads();

    // ---- phase 1: h = x @ w (register-staged), fused e_src/e_dst shfl reduction
    const int ho = tid % HF;
    const int h = ho / FOUT, o = ho % FOUT;
    const int n0 = tid / HF;
    float racc[ROWS];
    {
        float wcol[FIN];
        #pragma unroll
        for (int k = 0; k < FIN; ++k) wcol[k] = w[(h * FIN + k) * FOUT + o];
        const float as = asrc[ho], ad = adst[ho];
        #pragma unroll
        for (int r = 0; r < ROWS; ++r) {
            int n = n0 + r * NPT;
            float acc = 0.f;
            if (ROWS * NPT == NN || n < NN) {
                const float4* row = (const float4*)&sbuf[n * FIN];
                #pragma unroll
                for (int k4 = 0; k4 < FIN / 4; ++k4) {
                    float4 xv = row[k4];
                    acc += xv.x * wcol[4 * k4] + xv.y * wcol[4 * k4 + 1]
                         + xv.z * wcol[4 * k4 + 2] + xv.w * wcol[4 * k4 + 3];
                }
            }
            racc[r] = acc;
            float vs = acc * as, vd = acc * ad;
            #pragma unroll
            for (int off = FOUT / 2; off >= 1; off >>= 1) {
                vs += __shfl_xor(vs, off, 64);
                vd += __shfl_xor(vd, off, 64);
            }
            if (o == 0 && (ROWS * NPT == NN || n < NN)) {
                ses[h * NN + n] = vs; sed[h * NN + n] = vd;
            }
        }
    }
    __syncthreads();
    #pragma unroll
    for (int r = 0; r < ROWS; ++r) {
        int n = n0 + r * NPT;
        if (ROWS * NPT == NN || n < NN) sbuf[n * HF + ho] = racc[r];
    }
    __syncthreads();

    // ---- phase 2: single-pass masked softmax + aggregation
    constexpr int FT = FOUT / SPLIT;
    constexpr int ITEMS = H * NN * SPLIT;
    for (int idx = tid; idx < ITEMS; idx += 256) {
        int h2 = idx / (NN * SPLIT);
        int rem = idx % (NN * SPLIT);
        int n = rem / SPLIT;
        int os = (rem % SPLIT) * FT;
        unsigned long long m0 = smask[2 * n], m1 = smask[2 * n + 1];
        float esn = ses[h2 * NN + n];
        float denom = 0.f;
        float acc[FT];
        #pragma unroll
        for (int q = 0; q < FT; ++q) acc[q] = 0.f;
        const float4* sed4 = (const float4*)&sed[h2 * NN];
        #pragma unroll 2
        for (int g4 = 0; g4 < NN / 4; ++g4) {
            float4 ev = sed4[g4];
            unsigned int bits = (g4 < 16) ? (unsigned int)(m0 >> (4 * g4))
                                          : (unsigned int)(m1 >> (4 * g4 - 64));
            float e0 = esn + ev.x; e0 = (e0 > 0.f) ? e0 : 0.2f * e0;
            float e1 = esn + ev.y; e1 = (e1 > 0.f) ? e1 : 0.2f * e1;
            float e2 = esn + ev.z; e2 = (e2 > 0.f) ? e2 : 0.2f * e2;
            float e3 = esn + ev.w; e3 = (e3 > 0.f) ? e3 : 0.2f * e3;
            float p0 = (bits & 1u) ? __expf(e0) : 0.f;
            float p1 = (bits & 2u) ? __expf(e1) : 0.f;
            float p2 = (bits & 4u) ? __expf(e2) : 0.f;
            float p3 = (bits & 8u) ? __expf(e3) : 0.f;
            denom += (p0 + p1) + (p2 + p3);
            const float* r0 = &sbuf[(4 * g4 + 0) * HF + h2 * FOUT + os];
            const float* r1 = &sbuf[(4 * g4 + 1) * HF + h2 * FOUT + os];
            const float* r2 = &sbuf[(4 * g4 + 2) * HF + h2 * FOUT + os];
            const float* r3 = &sbuf[(4 * g4 + 3) * HF + h2 * FOUT + os];
            #pragma unroll
            for (int q4 = 0; q4 < FT / 4; ++q4) {
                float4 v0 = ((const float4*)r0)[q4];
                float4 v1 = ((const float4*)r1)[q4];
                float4 v2 = ((const float4*)r2)[q4];
                float4 v3 = ((const float4*)r3)[q4];
                acc[4 * q4 + 0] += p0 * v0.x + p1 * v1.x + p2 * v2.x + p3 * v3.x;
                acc[4 * q4 + 1] += p0 * v0.y + p1 * v1.y + p2 * v2.y + p3 * v3.y;
                acc[4 * q4 + 2] += p0 * v0.z + p1 * v1.z + p2 * v2.z + p3 * v3.z;
                acc[4 * q4 + 3] += p0 * v0.w + p1 * v1.w + p2 * v2.w + p3 * v3.w;
            }
        }
        float inv = 1.f / denom;
        if constexpr (OUTMODE == 0) {
            float4* op = (float4*)&out[((size_t)g * NN + n) * HF + h2 * FOUT + os];
            #pragma unroll
            for (int q4 = 0; q4 < FT / 4; ++q4) {
                float4 v;
                float a0 = acc[4 * q4 + 0] * inv + bias[h2 * FOUT + os + 4 * q4 + 0];
                float a1 = acc[4 * q4 + 1] * inv + bias[h2 * FOUT + os + 4 * q4 + 1];
                float a2 = acc[4 * q4 + 2] * inv + bias[h2 * FOUT + os + 4 * q4 + 2];
                float a3 = acc[4 * q4 + 3] * inv + bias[h2 * FOUT + os + 4 * q4 + 3];
                v.x = (a0 > 0.f) ? a0 : (__expf(a0) - 1.f);
                v.y = (a1 > 0.f) ? a1 : (__expf(a1) - 1.f);
                v.z = (a2 > 0.f) ? a2 : (__expf(a2) - 1.f);
                v.w = (a3 > 0.f) ? a3 : (__expf(a3) - 1.f);
                op[q4] = v;
            }
        } else if constexpr (OUTMODE == 1) {
            float4* op = (float4*)&out[((size_t)g * NN + n) * FOUT + os];
            #pragma unroll
            for (int q4 = 0; q4 < FT / 4; ++q4) {
                float4 v;
                v.x = acc[4 * q4 + 0] * inv + bias[os + 4 * q4 + 0];
                v.y = acc[4 * q4 + 1] * inv + bias[os + 4 * q4 + 1];
                v.z = acc[4 * q4 + 2] * inv + bias[os + 4 * q4 + 2];
                v.w = acc[4 * q4 + 3] * inv + bias[os + 4 * q4 + 3];
                op[q4] = v;
            }
        } else {
            size_t base = ((size_t)g * NN + n) * FOUT + os;
            float4* op = (float4*)&out[base];
            const float4* mp = (const float4*)&mgate[base];
            #pragma unroll
            for (int q4 = 0; q4 < FT / 4; ++q4) {
                float4 mv = mp[q4];
                float4 v;
                v.x = (acc[4 * q4 + 0] * inv + bias[os + 4 * q4 + 0]) * mv.x;
                v.y = (acc[4 * q4 + 1] * inv + bias[os + 4 * q4 + 1]) * mv.y;
                v.z = (acc[4 * q4 + 2] * inv + bias[os + 4 * q4 + 2]) * mv.z;
                v.w = (acc[4 * q4 + 3] * inv + bias[os + 4 * q4 + 3]) * mv.w;
                op[q4] = v;
            }
        }
    }
}

// ---------------------------------------------------------------- pool + reparameterize
__global__ void pool_kernel(const float* __restrict__ g2, const float* __restrict__ eps,
                            float* __restrict__ z, float* __restrict__ dout) {
    int g = blockIdx.x;
    int c = threadIdx.x;
    __shared__ float s[2 * LATF];
    if (c < 2 * LATF) {
        float sum = 0.f;
        for (int n = 0; n < NN; ++n) sum += g2[((size_t)g * NN + n) * (2 * LATF) + c];
        s[c] = sum * (1.f / NN);
    }
    __syncthreads();
    if (c < LATF) {
        float mu = s[c], lv = s[LATF + c];
        dout[640000 + (size_t)g * LATF + c] = mu;
        dout[652800 + (size_t)g * LATF + c] = lv;
        z[(size_t)g * LATF + c] = mu + eps[(size_t)g * LATF + c] * __expf(0.5f * lv);
    }
}

// ---------------------------------------------------------------- launch
extern "C" void kernel_launch(void* const* d_in, const int* in_sizes, int n_in,
                              void* d_out, int out_size, void* d_ws, size_t ws_size,
                              hipStream_t stream) {
    const float* o     = (const float*)d_in[0];
    const float* aprev = (const float*)d_in[1];
    const float* mk    = (const float*)d_in[2];
    const float* eps   = (const float*)d_in[3];
    const int*   adj   = (const int*)d_in[4];
    const float* Wobs  = (const float*)d_in[5];
    const float* bobs  = (const float*)d_in[6];
    const float* Wpa   = (const float*)d_in[7];
    const float* bpa   = (const float*)d_in[8];
    const float* Wmk   = (const float*)d_in[9];
    const float* bmk   = (const float*)d_in[10];
    const float* idemb = (const float*)d_in[11];
    const float* lWih  = (const float*)d_in[12];
    const float* lWhh  = (const float*)d_in[13];
    const float* lbih  = (const float*)d_in[14];
    const float* lbhh  = (const float*)d_in[15];
    const float* e1w = (const float*)d_in[16]; const float* e1s = (const float*)d_in[17];
    const float* e1d = (const float*)d_in[18]; const float* e1b = (const float*)d_in[19];
    const float* e2w = (const float*)d_in[20]; const float* e2s = (const float*)d_in[21];
    const float* e2d = (const float*)d_in[22]; const float* e2b = (const float*)d_in[23];
    const float* d1w = (const float*)d_in[24]; const float* d1s = (const float*)d_in[25];
    const float* d1d = (const float*)d_in[26]; const float* d1b = (const float*)d_in[27];
    const float* d2w = (const float*)d_in[28]; const float* d2s = (const float*)d_in[29];
    const float* d2d = (const float*)d_in[30]; const float* d2b = (const float*)d_in[31];
    const float* d3w = (const float*)d_in[32]; const float* d3s = (const float*)d_in[33];
    const float* d3d = (const float*)d_in[34]; const float* d3b = (const float*)d_in[35];

    float* ws   = (float*)d_ws;
    float* emb  = ws;
    float* xenc = ws + 5120000;
    float* xW   = ws + 10240000;       // dead after lstm
    float* g1o  = ws + 10240000;       // reuse of xW region
    float* g2o  = ws + 15360000;
    float* z    = ws + 17920000;
    float* d1o  = ws + 18000000;
    float* d2o  = ws + 23200000;
    unsigned long long* amask = (unsigned long long*)(ws + 30720000);
    float* out = (float*)d_out;

    adjmask_kernel<<<1, 128, 0, stream>>>(adj, amask);
    emb_kernel<<<BS * TT * NN, 64, 0, stream>>>(o, aprev, mk, Wobs, bobs, Wpa, bpa,
                                                Wmk, bmk, idemb, emb);
    xw_kernel<<<1600 * 5, 256, 0, stream>>>(emb, lWih, lbih, lbhh, xW);
    lstm_kernel<<<1600, 256, 0, stream>>>(xW, lWhh, xenc);
    gat_kernel<64, 0, 4, 16, 1, 0><<<800, 256, 0, stream>>>(xenc, nullptr, e1w, e1s, e1d, e1b,
                                                            amask, nullptr, g1o);
    gat_kernel<64, 0, 1, 32, 4, 1><<<800, 256, 0, stream>>>(g1o, nullptr, e2w, e2s, e2d, e2b,
                                                            amask, nullptr, g2o);
    pool_kernel<<<800, 64, 0, stream>>>(g2o, eps, z, out);
    gat_kernel<64, 16, 4, 16, 1, 0><<<800, 256, 0, stream>>>(emb, z, d1w, d1s, d1d, d1b,
                                                             amask, nullptr, d1o);
    gat_kernel<64, 0, 4, 16, 1, 0><<<800, 256, 0, stream>>>(d1o, nullptr, d2w, d2s, d2d, d2b,
                                                            amask, nullptr, d2o);
    gat_kernel<64, 0, 1, 8, 2, 2><<<800, 256, 0, stream>>>(d2o, nullptr, d3w, d3s, d3d, d3b,
                                                           amask, mk, out);
}

// Round 4
// 607.312 us; speedup vs baseline: 1.0500x; 1.0500x over previous
//
#include <hip/hip_runtime.h>

#define BS  16
#define TT  50
#define NN  100
#define OBSF 40
#define ACTF 8
#define HIDF 64
#define LATF 16

__device__ __forceinline__ float sigmf(float x) { return 1.f / (1.f + __expf(-x)); }
__device__ __forceinline__ float tanh_fast(float x) { return 1.f - 2.f / (__expf(2.f * x) + 1.f); }

// ---------------------------------------------------------------- adj bitmask
__global__ void adjmask_kernel(const int* __restrict__ adj, unsigned long long* __restrict__ mask) {
    int n = threadIdx.x;
    if (n < NN) {
        unsigned long long w0 = 0ull, w1 = 0ull;
        for (int m = 0; m < 64; ++m)  if (adj[n * NN + m] > 0) w0 |= (1ull << m);
        for (int m = 64; m < NN; ++m) if (adj[n * NN + m] > 0) w1 |= (1ull << (m - 64));
        mask[2 * n] = w0; mask[2 * n + 1] = w1;
    }
}

// ---------------------------------------------------------------- embedding
__global__ void emb_kernel(const float* __restrict__ o, const float* __restrict__ ap,
                           const float* __restrict__ mk,
                           const float* __restrict__ Wobs, const float* __restrict__ bobs,
                           const float* __restrict__ Wpa, const float* __restrict__ bpa,
                           const float* __restrict__ Wmk, const float* __restrict__ bmk,
                           const float* __restrict__ idemb, float* __restrict__ emb) {
    int g = blockIdx.x;               // (b*T+t)*N + n
    int n = g % NN;
    int j = threadIdx.x;              // 0..63
    __shared__ float so[OBSF], sa[ACTF], sm[ACTF];
    if (j < OBSF) so[j] = o[(size_t)g * OBSF + j];
    if (j >= 40 && j < 48) sa[j - 40] = ap[(size_t)g * ACTF + (j - 40)];
    if (j >= 48 && j < 56) sm[j - 48] = mk[(size_t)g * ACTF + (j - 48)];
    __syncthreads();
    float acc = bobs[j] + bpa[j] + bmk[j] + idemb[n * HIDF + j];
    #pragma unroll
    for (int k = 0; k < OBSF; ++k) acc += so[k] * Wobs[k * HIDF + j];
    #pragma unroll
    for (int k = 0; k < ACTF; ++k) acc += sa[k] * Wpa[k * HIDF + j] + sm[k] * Wmk[k * HIDF + j];
    emb[(size_t)g * HIDF + j] = acc;
}

// ---------------------------------------------------------------- xW = x @ Wih + bih + bhh
__global__ void xw_kernel(const float* __restrict__ emb, const float* __restrict__ Wih,
                          const float* __restrict__ bih, const float* __restrict__ bhh,
                          float* __restrict__ xW) {
    int blk = blockIdx.x;
    int chunk = blk % 5;
    int s = blk / 5;
    int b = s / NN, n = s % NN;
    int t0 = chunk * 10;
    __shared__ float se[10][HIDF];
    int tid = threadIdx.x;
    for (int i = tid; i < 10 * HIDF; i += 256) {
        int r = i >> 6, k = i & 63;
        se[r][k] = emb[((size_t)(b * TT + t0 + r) * NN + n) * HIDF + k];
    }
    __syncthreads();
    int j = tid;
    float base = bih[j] + bhh[j];
    float acc[10];
    #pragma unroll
    for (int r = 0; r < 10; ++r) acc[r] = base;
    for (int k = 0; k < HIDF; ++k) {
        float w = Wih[k * 256 + j];
        #pragma unroll
        for (int r = 0; r < 10; ++r) acc[r] += se[r][k] * w;
    }
    #pragma unroll
    for (int r = 0; r < 10; ++r) xW[((size_t)s * TT + t0 + r) * 256 + j] = acc[r];
}

// ---------------------------------------------------------------- LSTM recurrence
// ONE barrier per timestep:
//  - each wave keeps a private LDS copy hs[wave][64] of h (written wave-
//    synchronously by its own lanes; no cross-wave dependency on h)
//  - gemv reads h via broadcast ds_read_b128 from own wave's copy, with 4
//    independent accumulators (breaks the serial fp32 FMA chain)
//  - gate values go through parity-double-buffered gs + one __syncthreads()
//  - all 4 waves redundantly compute the activations (identical inputs),
//    wave 0 stores xenc
__launch_bounds__(256)
__global__ void lstm_kernel(const float* __restrict__ xW, const float* __restrict__ Whh,
                            float* __restrict__ xenc) {
    int s = blockIdx.x;
    int b = s / NN, n = s % NN;
    int tid = threadIdx.x;
    int wave = tid >> 6, lane = tid & 63;
    __shared__ __align__(16) float hs[4][HIDF];
    __shared__ float gs[2][256];
    float wcol[HIDF];
    #pragma unroll
    for (int k = 0; k < HIDF; ++k) wcol[k] = Whh[k * 256 + tid];
    hs[wave][lane] = 0.f;
    float c = 0.f;
    const float* xp = xW + (size_t)s * TT * 256 + tid;
    float* xe = xenc + ((size_t)b * TT * NN + n) * HIDF + lane;
    for (int t = 0; t < TT; ++t) {
        float xv = xp[(size_t)t * 256];
        const float4* h4 = (const float4*)hs[wave];
        float a0 = 0.f, a1 = 0.f, a2 = 0.f, a3 = 0.f;
        #pragma unroll
        for (int k4 = 0; k4 < 4; ++k4) {
            float4 v0 = h4[4 * k4 + 0];
            float4 v1 = h4[4 * k4 + 1];
            float4 v2 = h4[4 * k4 + 2];
            float4 v3 = h4[4 * k4 + 3];
            a0 += v0.x * wcol[16 * k4 + 0] + v0.y * wcol[16 * k4 + 1]
                + v0.z * wcol[16 * k4 + 2] + v0.w * wcol[16 * k4 + 3];
            a1 += v1.x * wcol[16 * k4 + 4] + v1.y * wcol[16 * k4 + 5]
                + v1.z * wcol[16 * k4 + 6] + v1.w * wcol[16 * k4 + 7];
            a2 += v2.x * wcol[16 * k4 + 8] + v2.y * wcol[16 * k4 + 9]
                + v2.z * wcol[16 * k4 + 10] + v2.w * wcol[16 * k4 + 11];
            a3 += v3.x * wcol[16 * k4 + 12] + v3.y * wcol[16 * k4 + 13]
                + v3.z * wcol[16 * k4 + 14] + v3.w * wcol[16 * k4 + 15];
        }
        gs[t & 1][tid] = xv + (a0 + a1) + (a2 + a3);
        __syncthreads();
        float gi = gs[t & 1][lane];
        float gf = gs[t & 1][64 + lane];
        float gg = gs[t & 1][128 + lane];
        float go = gs[t & 1][192 + lane];
        c = sigmf(gf) * c + sigmf(gi) * tanh_fast(gg);
        float h = sigmf(go) * tanh_fast(c);
        hs[wave][lane] = h;
        if (wave == 0) xe[(size_t)t * NN * HIDF] = h;
    }
}

// ---------------------------------------------------------------- fused GAT layer
// sh aliases sx (phase-1 result staged in registers). Single-pass softmax (no max),
// branchless mask, float4 LDS/global. SPLIT divides FOUT across threads in phase 2.
// OUTMODE 0: concat heads + elu(+bias); 1: single head + bias; 2: +bias then * mgate
template <int FIN1, int FIN2, int H, int FOUT, int SPLIT, int OUTMODE>
__launch_bounds__(256)
__global__ void gat_kernel(const float* __restrict__ x1, const float* __restrict__ x2,
                           const float* __restrict__ w, const float* __restrict__ asrc,
                           const float* __restrict__ adst, const float* __restrict__ bias,
                           const unsigned long long* __restrict__ adjmask,
                           const float* __restrict__ mgate, float* __restrict__ out) {
    constexpr int FIN = FIN1 + FIN2;
    constexpr int HF = H * FOUT;
    constexpr int NPT = 256 / HF;                    // rows in flight (4 / 8 / 32)
    constexpr int ROWS = (NN + NPT - 1) / NPT;       // 25 / 13 / 4
    constexpr int SB = NN * (FIN > HF ? FIN : HF);
    __shared__ __align__(16) float sbuf[SB];         // sx, later aliased as sh
    __shared__ __align__(16) float ses[H * NN];
    __shared__ __align__(16) float sed[H * NN];
    __shared__ unsigned long long smask[2 * NN];
    int g = blockIdx.x;
    int tid = threadIdx.x;

    for (int i = tid; i < NN * FIN1; i += 256) {
        int n = i / FIN1, k = i % FIN1;
        sbuf[n * FIN + k] = x1[((size_t)g * NN + n) * FIN1 + k];
    }
    if constexpr (FIN2 > 0) {
        for (int i = tid; i < NN * FIN2; i += 256) {
            int n = i / FIN2, k = i % FIN2;
            sbuf[n * FIN + FIN1 + k] = x2[(size_t)g * FIN2 + k];
        }
    }
    if (tid < 2 * NN) smask[tid] = adjmask[tid];
    __syncthreads();

    // ---- phase 1: h = x @ w (register-staged), fused e_src/e_dst shfl reduction
    const int ho = tid % HF;
    const int h = ho / FOUT, o = ho % FOUT;
    const int n0 = tid / HF;
    float racc[ROWS];
    {
        float wcol[FIN];
        #pragma unroll
        for (int k = 0; k < FIN; ++k) wcol[k] = w[(h * FIN + k) * FOUT + o];
        const float as = asrc[ho], ad = adst[ho];
        #pragma unroll
        for (int r = 0; r < ROWS; ++r) {
            int n = n0 + r * NPT;
            float acc = 0.f;
            if (ROWS * NPT == NN || n < NN) {
                const float4* row = (const float4*)&sbuf[n * FIN];
                #pragma unroll
                for (int k4 = 0; k4 < FIN / 4; ++k4) {
                    float4 xv = row[k4];
                    acc += xv.x * wcol[4 * k4] + xv.y * wcol[4 * k4 + 1]
                         + xv.z * wcol[4 * k4 + 2] + xv.w * wcol[4 * k4 + 3];
                }
            }
            racc[r] = acc;
            float vs = acc * as, vd = acc * ad;
            #pragma unroll
            for (int off = FOUT / 2; off >= 1; off >>= 1) {
                vs += __shfl_xor(vs, off, 64);
                vd += __shfl_xor(vd, off, 64);
            }
            if (o == 0 && (ROWS * NPT == NN || n < NN)) {
                ses[h * NN + n] = vs; sed[h * NN + n] = vd;
            }
        }
    }
    __syncthreads();
    #pragma unroll
    for (int r = 0; r < ROWS; ++r) {
        int n = n0 + r * NPT;
        if (ROWS * NPT == NN || n < NN) sbuf[n * HF + ho] = racc[r];
    }
    __syncthreads();

    // ---- phase 2: single-pass masked softmax + aggregation
    constexpr int FT = FOUT / SPLIT;
    constexpr int ITEMS = H * NN * SPLIT;
    for (int idx = tid; idx < ITEMS; idx += 256) {
        int h2 = idx / (NN * SPLIT);
        int rem = idx % (NN * SPLIT);
        int n = rem / SPLIT;
        int os = (rem % SPLIT) * FT;
        unsigned long long m0 = smask[2 * n], m1 = smask[2 * n + 1];
        float esn = ses[h2 * NN + n];
        float denom = 0.f;
        float acc[FT];
        #pragma unroll
        for (int q = 0; q < FT; ++q) acc[q] = 0.f;
        const float4* sed4 = (const float4*)&sed[h2 * NN];
        #pragma unroll 2
        for (int g4 = 0; g4 < NN / 4; ++g4) {
            float4 ev = sed4[g4];
            unsigned int bits = (g4 < 16) ? (unsigned int)(m0 >> (4 * g4))
                                          : (unsigned int)(m1 >> (4 * g4 - 64));
            float e0 = esn + ev.x; e0 = (e0 > 0.f) ? e0 : 0.2f * e0;
            float e1 = esn + ev.y; e1 = (e1 > 0.f) ? e1 : 0.2f * e1;
            float e2 = esn + ev.z; e2 = (e2 > 0.f) ? e2 : 0.2f * e2;
            float e3 = esn + ev.w; e3 = (e3 > 0.f) ? e3 : 0.2f * e3;
            float p0 = (bits & 1u) ? __expf(e0) : 0.f;
            float p1 = (bits & 2u) ? __expf(e1) : 0.f;
            float p2 = (bits & 4u) ? __expf(e2) : 0.f;
            float p3 = (bits & 8u) ? __expf(e3) : 0.f;
            denom += (p0 + p1) + (p2 + p3);
            const float* r0 = &sbuf[(4 * g4 + 0) * HF + h2 * FOUT + os];
            const float* r1 = &sbuf[(4 * g4 + 1) * HF + h2 * FOUT + os];
            const float* r2 = &sbuf[(4 * g4 + 2) * HF + h2 * FOUT + os];
            const float* r3 = &sbuf[(4 * g4 + 3) * HF + h2 * FOUT + os];
            #pragma unroll
            for (int q4 = 0; q4 < FT / 4; ++q4) {
                float4 v0 = ((const float4*)r0)[q4];
                float4 v1 = ((const float4*)r1)[q4];
                float4 v2 = ((const float4*)r2)[q4];
                float4 v3 = ((const float4*)r3)[q4];
                acc[4 * q4 + 0] += p0 * v0.x + p1 * v1.x + p2 * v2.x + p3 * v3.x;
                acc[4 * q4 + 1] += p0 * v0.y + p1 * v1.y + p2 * v2.y + p3 * v3.y;
                acc[4 * q4 + 2] += p0 * v0.z + p1 * v1.z + p2 * v2.z + p3 * v3.z;
                acc[4 * q4 + 3] += p0 * v0.w + p1 * v1.w + p2 * v2.w + p3 * v3.w;
            }
        }
        float inv = 1.f / denom;
        if constexpr (OUTMODE == 0) {
            float4* op = (float4*)&out[((size_t)g * NN + n) * HF + h2 * FOUT + os];
            #pragma unroll
            for (int q4 = 0; q4 < FT / 4; ++q4) {
                float4 v;
                float a0 = acc[4 * q4 + 0] * inv + bias[h2 * FOUT + os + 4 * q4 + 0];
                float a1 = acc[4 * q4 + 1] * inv + bias[h2 * FOUT + os + 4 * q4 + 1];
                float a2 = acc[4 * q4 + 2] * inv + bias[h2 * FOUT + os + 4 * q4 + 2];
                float a3 = acc[4 * q4 + 3] * inv + bias[h2 * FOUT + os + 4 * q4 + 3];
                v.x = (a0 > 0.f) ? a0 : (__expf(a0) - 1.f);
                v.y = (a1 > 0.f) ? a1 : (__expf(a1) - 1.f);
                v.z = (a2 > 0.f) ? a2 : (__expf(a2) - 1.f);
                v.w = (a3 > 0.f) ? a3 : (__expf(a3) - 1.f);
                op[q4] = v;
            }
        } else if constexpr (OUTMODE == 1) {
            float4* op = (float4*)&out[((size_t)g * NN + n) * FOUT + os];
            #pragma unroll
            for (int q4 = 0; q4 < FT / 4; ++q4) {
                float4 v;
                v.x = acc[4 * q4 + 0] * inv + bias[os + 4 * q4 + 0];
                v.y = acc[4 * q4 + 1] * inv + bias[os + 4 * q4 + 1];
                v.z = acc[4 * q4 + 2] * inv + bias[os + 4 * q4 + 2];
                v.w = acc[4 * q4 + 3] * inv + bias[os + 4 * q4 + 3];
                op[q4] = v;
            }
        } else {
            size_t base = ((size_t)g * NN + n) * FOUT + os;
            float4* op = (float4*)&out[base];
            const float4* mp = (const float4*)&mgate[base];
            #pragma unroll
            for (int q4 = 0; q4 < FT / 4; ++q4) {
                float4 mv = mp[q4];
                float4 v;
                v.x = (acc[4 * q4 + 0] * inv + bias[os + 4 * q4 + 0]) * mv.x;
                v.y = (acc[4 * q4 + 1] * inv + bias[os + 4 * q4 + 1]) * mv.y;
                v.z = (acc[4 * q4 + 2] * inv + bias[os + 4 * q4 + 2]) * mv.z;
                v.w = (acc[4 * q4 + 3] * inv + bias[os + 4 * q4 + 3]) * mv.w;
                op[q4] = v;
            }
        }
    }
}

// ---------------------------------------------------------------- pool + reparameterize
__global__ void pool_kernel(const float* __restrict__ g2, const float* __restrict__ eps,
                            float* __restrict__ z, float* __restrict__ dout) {
    int g = blockIdx.x;
    int c = threadIdx.x;
    __shared__ float s[2 * LATF];
    if (c < 2 * LATF) {
        float sum = 0.f;
        for (int n = 0; n < NN; ++n) sum += g2[((size_t)g * NN + n) * (2 * LATF) + c];
        s[c] = sum * (1.f / NN);
    }
    __syncthreads();
    if (c < LATF) {
        float mu = s[c], lv = s[LATF + c];
        dout[640000 + (size_t)g * LATF + c] = mu;
        dout[652800 + (size_t)g * LATF + c] = lv;
        z[(size_t)g * LATF + c] = mu + eps[(size_t)g * LATF + c] * __expf(0.5f * lv);
    }
}

// ---------------------------------------------------------------- launch
extern "C" void kernel_launch(void* const* d_in, const int* in_sizes, int n_in,
                              void* d_out, int out_size, void* d_ws, size_t ws_size,
                              hipStream_t stream) {
    const float* o     = (const float*)d_in[0];
    const float* aprev = (const float*)d_in[1];
    const float* mk    = (const float*)d_in[2];
    const float* eps   = (const float*)d_in[3];
    const int*   adj   = (const int*)d_in[4];
    const float* Wobs  = (const float*)d_in[5];
    const float* bobs  = (const float*)d_in[6];
    const float* Wpa   = (const float*)d_in[7];
    const float* bpa   = (const float*)d_in[8];
    const float* Wmk   = (const float*)d_in[9];
    const float* bmk   = (const float*)d_in[10];
    const float* idemb = (const float*)d_in[11];
    const float* lWih  = (const float*)d_in[12];
    const float* lWhh  = (const float*)d_in[13];
    const float* lbih  = (const float*)d_in[14];
    const float* lbhh  = (const float*)d_in[15];
    const float* e1w = (const float*)d_in[16]; const float* e1s = (const float*)d_in[17];
    const float* e1d = (const float*)d_in[18]; const float* e1b = (const float*)d_in[19];
    const float* e2w = (const float*)d_in[20]; const float* e2s = (const float*)d_in[21];
    const float* e2d = (const float*)d_in[22]; const float* e2b = (const float*)d_in[23];
    const float* d1w = (const float*)d_in[24]; const float* d1s = (const float*)d_in[25];
    const float* d1d = (const float*)d_in[26]; const float* d1b = (const float*)d_in[27];
    const float* d2w = (const float*)d_in[28]; const float* d2s = (const float*)d_in[29];
    const float* d2d = (const float*)d_in[30]; const float* d2b = (const float*)d_in[31];
    const float* d3w = (const float*)d_in[32]; const float* d3s = (const float*)d_in[33];
    const float* d3d = (const float*)d_in[34]; const float* d3b = (const float*)d_in[35];

    float* ws   = (float*)d_ws;
    float* emb  = ws;
    float* xenc = ws + 5120000;
    float* xW   = ws + 10240000;       // dead after lstm
    float* g1o  = ws + 10240000;       // reuse of xW region
    float* g2o  = ws + 15360000;
    float* z    = ws + 17920000;
    float* d1o  = ws + 18000000;
    float* d2o  = ws + 23200000;
    unsigned long long* amask = (unsigned long long*)(ws + 30720000);
    float* out = (float*)d_out;

    adjmask_kernel<<<1, 128, 0, stream>>>(adj, amask);
    emb_kernel<<<BS * TT * NN, 64, 0, stream>>>(o, aprev, mk, Wobs, bobs, Wpa, bpa,
                                                Wmk, bmk, idemb, emb);
    xw_kernel<<<1600 * 5, 256, 0, stream>>>(emb, lWih, lbih, lbhh, xW);
    lstm_kernel<<<1600, 256, 0, stream>>>(xW, lWhh, xenc);
    gat_kernel<64, 0, 4, 16, 1, 0><<<800, 256, 0, stream>>>(xenc, nullptr, e1w, e1s, e1d, e1b,
                                                            amask, nullptr, g1o);
    gat_kernel<64, 0, 1, 32, 4, 1><<<800, 256, 0, stream>>>(g1o, nullptr, e2w, e2s, e2d, e2b,
                                                            amask, nullptr, g2o);
    pool_kernel<<<800, 64, 0, stream>>>(g2o, eps, z, out);
    gat_kernel<64, 16, 4, 16, 1, 0><<<800, 256, 0, stream>>>(emb, z, d1w, d1s, d1d, d1b,
                                                             amask, nullptr, d1o);
    gat_kernel<64, 0, 4, 16, 1, 0><<<800, 256, 0, stream>>>(d1o, nullptr, d2w, d2s, d2d, d2b,
                                                            amask, nullptr, d2o);
    gat_kernel<64, 0, 1, 8, 2, 2><<<800, 256, 0, stream>>>(d2o, nullptr, d3w, d3s, d3d, d3b,
                                                           amask, mk, out);
}